// Round 9
// baseline (197.032 us; speedup 1.0000x reference)
//
#include <hip/hip_runtime.h>
#include <hip/hip_bf16.h>
#include <math.h>

#define N_NODES 50000
#define N_EDGES 800000
#define NEG_SLOPE 0.2f
#define NBUCK ((N_NODES + 255) / 256)   // 196 buckets of 256 dsts
#define CCHUNK 4096
#define DCAP 8192

__device__ inline float lrelu(float x) { return fmaxf(x, NEG_SLOPE * x); }

__device__ inline unsigned bf16rne(float f) {
    unsigned u = __float_as_uint(f);
    return (u + 0x7fffu + ((u >> 16) & 1u)) >> 16;
}

// ---------------- CSR build: LDS-staged bucket sort ----------------
__global__ void zerobuf_kernel(int* __restrict__ p) {
    int i = threadIdx.x;
    if (i < NBUCK) p[i] = 0;
}

__global__ __launch_bounds__(256) void bucketcount_kernel(const int* __restrict__ ei,
                                                          int* __restrict__ gbcnt) {
    __shared__ int lc[NBUCK];
    for (int i = threadIdx.x; i < NBUCK; i += 256) lc[i] = 0;
    __syncthreads();
    int stride = gridDim.x * 256;
    for (int e = blockIdx.x * 256 + threadIdx.x; e < N_EDGES; e += stride)
        atomicAdd(&lc[ei[N_EDGES + e] >> 8], 1);
    __syncthreads();
    for (int i = threadIdx.x; i < NBUCK; i += 256)
        if (lc[i]) atomicAdd(&gbcnt[i], lc[i]);
}

__global__ __launch_bounds__(256) void bucketscan_kernel(const int* __restrict__ gbcnt,
                                                         int* __restrict__ bbase,
                                                         int* __restrict__ bcur) {
    __shared__ int ss[256];
    int t = threadIdx.x;
    int v = (t < NBUCK) ? gbcnt[t] : 0;
    ss[t] = v;
    __syncthreads();
    for (int d = 1; d < 256; d <<= 1) {
        int u = (t >= d) ? ss[t - d] : 0;
        __syncthreads();
        ss[t] += u;
        __syncthreads();
    }
    int excl = ss[t] - v;
    if (t < NBUCK) { bbase[t] = excl; bcur[t] = excl; }
    if (t == 0) bbase[NBUCK] = N_EDGES;
}

__global__ __launch_bounds__(256) void bucketscatter_kernel(const int* __restrict__ ei,
                                                            int* __restrict__ bcur,
                                                            int2* __restrict__ bpairs) {
    __shared__ int cnt[NBUCK], startl[NBUCK], baseg[NBUCK], cur2[NBUCK];
    __shared__ int ss[256];
    __shared__ int2 stage[CCHUNK];
    int t = threadIdx.x;
    int e0 = blockIdx.x * CCHUNK;
    int nume = min(CCHUNK, N_EDGES - e0);
    for (int i = t; i < NBUCK; i += 256) { cnt[i] = 0; cur2[i] = 0; }
    __syncthreads();
    int src[CCHUNK / 256], dst[CCHUNK / 256];
    #pragma unroll
    for (int j = 0; j < CCHUNK / 256; ++j) {
        int idx = t + j * 256;
        if (idx < nume) {
            src[j] = ei[e0 + idx];
            dst[j] = ei[N_EDGES + e0 + idx];
            atomicAdd(&cnt[dst[j] >> 8], 1);
        } else dst[j] = -1;
    }
    __syncthreads();
    {
        int v = (t < NBUCK) ? cnt[t] : 0;
        ss[t] = v;
        __syncthreads();
        for (int d = 1; d < 256; d <<= 1) {
            int u = (t >= d) ? ss[t - d] : 0;
            __syncthreads();
            ss[t] += u;
            __syncthreads();
        }
        if (t < NBUCK) startl[t] = ss[t] - v;
    }
    __syncthreads();
    if (t < NBUCK && cnt[t] > 0) baseg[t] = atomicAdd(&bcur[t], cnt[t]);
    __syncthreads();
    #pragma unroll
    for (int j = 0; j < CCHUNK / 256; ++j) {
        if (dst[j] >= 0) {
            int b = dst[j] >> 8;
            int slot = startl[b] + atomicAdd(&cur2[b], 1);
            stage[slot] = make_int2(src[j], dst[j]);
        }
    }
    __syncthreads();
    for (int i = t; i < nume; i += 256) {
        int2 p = stage[i];
        int b = p.y >> 8;
        bpairs[baseg[b] + (i - startl[b])] = p;
    }
}

__global__ __launch_bounds__(256) void csrfinalize_kernel(const int2* __restrict__ bpairs,
                                                          const int* __restrict__ bbase,
                                                          int* __restrict__ ptr,
                                                          int* __restrict__ csr) {
    __shared__ int cnt[256], excl[256], cur[256];
    __shared__ int ss[256];
    __shared__ int2 P[DCAP];
    int b = blockIdx.x, t = threadIdx.x;
    int bb = bbase[b], be = bbase[b + 1];
    int n = be - bb;
    int d0 = b << 8;
    int dmax = min(256, N_NODES - d0);
    bool fits = (n <= DCAP);
    cnt[t] = 0; cur[t] = 0;
    __syncthreads();
    for (int i = t; i < n; i += 256) {
        int2 p = bpairs[bb + i];
        if (fits) P[i] = p;
        atomicAdd(&cnt[p.y & 255], 1);
    }
    __syncthreads();
    {
        int v = cnt[t];
        ss[t] = v;
        __syncthreads();
        for (int d = 1; d < 256; d <<= 1) {
            int u = (t >= d) ? ss[t - d] : 0;
            __syncthreads();
            ss[t] += u;
            __syncthreads();
        }
        excl[t] = ss[t] - v;
    }
    __syncthreads();
    if (t < dmax) ptr[d0 + t] = bb + excl[t];
    if (b == NBUCK - 1 && t == 0) ptr[N_NODES] = N_EDGES;
    for (int i = t; i < n; i += 256) {
        int2 p = fits ? P[i] : bpairs[bb + i];
        int ld = p.y & 255;
        int pos = bb + excl[ld] + atomicAdd(&cur[ld], 1);
        csr[pos] = p.x;
    }
}

// ---- GEMM + fused attention-logit epilogue (32 rows/block for occupancy) ----
#define GB_ROWS 32
template <int H>
__global__ __launch_bounds__(256) void gemm_kernel(const float* __restrict__ X,
                                                   const float* __restrict__ W,
                                                   const float* __restrict__ asrc,
                                                   const float* __restrict__ adst,
                                                   unsigned short* __restrict__ Hb,
                                                   float* __restrict__ als,
                                                   float* __restrict__ ald,
                                                   int nrows) {
    __shared__ float xt[GB_ROWS][132];
    const int tid = threadIdx.x;
    const int r0 = blockIdx.x * GB_ROWS;
    #pragma unroll
    for (int i = 0; i < 4; ++i) {
        int idx = tid + 256 * i;          // 0..1023 float4 slots
        int r = idx >> 5, c4 = (idx & 31) * 4;
        int gr = r0 + r;
        float4 v = make_float4(0.f, 0.f, 0.f, 0.f);
        if (gr < nrows) v = *(const float4*)(X + (size_t)gr * 128 + c4);
        *(float4*)(&xt[r][c4]) = v;
    }
    __syncthreads();
    const int c0 = (tid & 31) * 4;
    const int rbase = (tid >> 5) * 4;     // 8 groups x 4 rows
    const int q = tid & 31;
    float acc[4][4];
    #pragma unroll
    for (int i = 0; i < 4; ++i)
        #pragma unroll
        for (int j = 0; j < 4; ++j) acc[i][j] = 0.f;
    #pragma unroll 4
    for (int k = 0; k < 128; ++k) {
        float4 w4 = *(const float4*)(W + k * 128 + c0);
        float xv[4];
        #pragma unroll
        for (int i = 0; i < 4; ++i) xv[i] = xt[rbase + i][k];
        #pragma unroll
        for (int i = 0; i < 4; ++i) {
            acc[i][0] = fmaf(xv[i], w4.x, acc[i][0]);
            acc[i][1] = fmaf(xv[i], w4.y, acc[i][1]);
            acc[i][2] = fmaf(xv[i], w4.z, acc[i][2]);
            acc[i][3] = fmaf(xv[i], w4.w, acc[i][3]);
        }
    }
    float4 as4 = *(const float4*)(asrc + c0);
    float4 ad4 = *(const float4*)(adst + c0);
    #pragma unroll
    for (int i = 0; i < 4; ++i) {
        int gr = r0 + rbase + i;
        bool ok = gr < nrows;
        if (ok) {
            uint2 p;
            p.x = bf16rne(acc[i][0]) | (bf16rne(acc[i][1]) << 16);
            p.y = bf16rne(acc[i][2]) | (bf16rne(acc[i][3]) << 16);
            *(uint2*)(Hb + (size_t)gr * 128 + c0) = p;
        }
        float sp = acc[i][0] * as4.x + acc[i][1] * as4.y + acc[i][2] * as4.z + acc[i][3] * as4.w;
        float dp = acc[i][0] * ad4.x + acc[i][1] * ad4.y + acc[i][2] * ad4.z + acc[i][3] * ad4.w;
        #pragma unroll
        for (int off = 1; off < (H == 2 ? 16 : 32); off <<= 1) {
            sp += __shfl_xor(sp, off);
            dp += __shfl_xor(dp, off);
        }
        if (ok) {
            if (H == 2) {
                if (q == 0)  { als[(size_t)gr * 2]     = sp; ald[(size_t)gr * 2]     = dp; }
                if (q == 16) { als[(size_t)gr * 2 + 1] = sp; ald[(size_t)gr * 2 + 1] = dp; }
            } else {
                if (q == 0) { als[gr] = sp; ald[gr] = dp; }
            }
        }
    }
}

// ---- fused softmax+gather: lane-parallel softmax, LDS-broadcast gather ----
template <int H, int DO_ELU>
__global__ __launch_bounds__(256) void aggregate_kernel(const unsigned short* __restrict__ Hb,
                                                        const float* __restrict__ als,
                                                        const float* __restrict__ aldv,
                                                        const int* __restrict__ ptr,
                                                        const int* __restrict__ csr,
                                                        const float* __restrict__ bias,
                                                        float* __restrict__ out) {
    __shared__ int   s_src[4][64];
    __shared__ float s_p[4][H][64];
    const int w = threadIdx.x >> 6;
    const int lane = threadIdx.x & 63;
    const int d = blockIdx.x * 4 + w;
    if (d >= N_NODES) return;
    const int head = (H == 2) ? (lane >> 5) : 0;

    int beg = ptr[d], end = ptr[d + 1];

    float ald0, ald1 = 0.f, es0, es1 = 0.f;
    if (H == 2) {
        float2 ta = *(const float2*)(aldv + (size_t)d * 2);
        float2 ts = *(const float2*)(als + (size_t)d * 2);
        ald0 = ta.x; ald1 = ta.y;
        es0 = lrelu(ts.x + ald0); es1 = lrelu(ts.y + ald1);
    } else {
        ald0 = aldv[d]; es0 = lrelu(als[d] + ald0);
    }

    // phase 0: lane-parallel logits + wave max
    int k0 = beg + lane;
    int src0 = 0;
    float e0 = -INFINITY, e1 = -INFINITY;
    if (k0 < end) {
        src0 = csr[k0];
        if (H == 2) {
            float2 t = *(const float2*)(als + (size_t)src0 * 2);
            e0 = lrelu(t.x + ald0); e1 = lrelu(t.y + ald1);
        } else e0 = lrelu(als[src0] + ald0);
    }
    float m0 = fmaxf(es0, e0);
    float m1 = (H == 2) ? fmaxf(es1, e1) : 0.f;
    for (int k = k0 + 64; k < end; k += 64) {   // deg>64: rare recompute path
        int s = csr[k];
        if (H == 2) {
            float2 t = *(const float2*)(als + (size_t)s * 2);
            m0 = fmaxf(m0, lrelu(t.x + ald0));
            m1 = fmaxf(m1, lrelu(t.y + ald1));
        } else m0 = fmaxf(m0, lrelu(als[s] + ald0));
    }
    #pragma unroll
    for (int off = 32; off; off >>= 1) {
        m0 = fmaxf(m0, __shfl_xor(m0, off));
        if (H == 2) m1 = fmaxf(m1, __shfl_xor(m1, off));
    }

    float l0 = 0.f, l1 = 0.f;
    float ax[8], ay[8];
    #pragma unroll
    for (int i = 0; i < 8; ++i) { ax[i] = 0.f; ay[i] = 0.f; }

    for (int t0 = beg; t0 < end; t0 += 64) {
        int cnt = min(64, end - t0);
        // phase A: produce p for this tile (one lane per edge)
        int k = t0 + lane;
        if (k < end) {
            int s; float f0, f1 = 0.f;
            if (t0 == beg) { s = src0; f0 = e0; f1 = e1; }
            else {
                s = csr[k];
                if (H == 2) {
                    float2 t = *(const float2*)(als + (size_t)s * 2);
                    f0 = lrelu(t.x + ald0); f1 = lrelu(t.y + ald1);
                } else f0 = lrelu(als[s] + ald0);
            }
            float p0 = __expf(f0 - m0);
            l0 += p0;
            s_src[w][lane] = s;
            s_p[w][0][lane] = p0;
            if (H == 2) {
                float p1 = __expf(f1 - m1);
                l1 += p1;
                s_p[w][1][lane] = p1;
            }
        }
        // phase B: all lanes gather cnt edges; 8 independent load/acc chains
        int j = 0;
        for (; j + 7 < cnt; j += 8) {
            int ss[8]; float pp[8]; unsigned uu[8];
            #pragma unroll
            for (int i = 0; i < 8; ++i) { ss[i] = s_src[w][j + i]; pp[i] = s_p[w][head][j + i]; }
            #pragma unroll
            for (int i = 0; i < 8; ++i) uu[i] = ((const unsigned*)(Hb + (size_t)ss[i] * 128))[lane];
            #pragma unroll
            for (int i = 0; i < 8; ++i) {
                ax[i] = fmaf(pp[i], __uint_as_float(uu[i] << 16), ax[i]);
                ay[i] = fmaf(pp[i], __uint_as_float(uu[i] & 0xffff0000u), ay[i]);
            }
        }
        if (j + 3 < cnt) {
            int ss[4]; float pp[4]; unsigned uu[4];
            #pragma unroll
            for (int i = 0; i < 4; ++i) { ss[i] = s_src[w][j + i]; pp[i] = s_p[w][head][j + i]; }
            #pragma unroll
            for (int i = 0; i < 4; ++i) uu[i] = ((const unsigned*)(Hb + (size_t)ss[i] * 128))[lane];
            #pragma unroll
            for (int i = 0; i < 4; ++i) {
                ax[i] = fmaf(pp[i], __uint_as_float(uu[i] << 16), ax[i]);
                ay[i] = fmaf(pp[i], __uint_as_float(uu[i] & 0xffff0000u), ay[i]);
            }
            j += 4;
        }
        if (j + 1 < cnt) {
            int ss[2]; float pp[2]; unsigned uu[2];
            #pragma unroll
            for (int i = 0; i < 2; ++i) { ss[i] = s_src[w][j + i]; pp[i] = s_p[w][head][j + i]; }
            #pragma unroll
            for (int i = 0; i < 2; ++i) uu[i] = ((const unsigned*)(Hb + (size_t)ss[i] * 128))[lane];
            #pragma unroll
            for (int i = 0; i < 2; ++i) {
                ax[i] = fmaf(pp[i], __uint_as_float(uu[i] << 16), ax[i]);
                ay[i] = fmaf(pp[i], __uint_as_float(uu[i] & 0xffff0000u), ay[i]);
            }
            j += 2;
        }
        if (j < cnt) {
            int sA = s_src[w][j];
            float pA = s_p[w][head][j];
            unsigned uA = ((const unsigned*)(Hb + (size_t)sA * 128))[lane];
            ax[0] = fmaf(pA, __uint_as_float(uA << 16), ax[0]);
            ay[0] = fmaf(pA, __uint_as_float(uA & 0xffff0000u), ay[0]);
        }
    }

    float axs = ((ax[0] + ax[1]) + (ax[2] + ax[3])) + ((ax[4] + ax[5]) + (ax[6] + ax[7]));
    float ays = ((ay[0] + ay[1]) + (ay[2] + ay[3])) + ((ay[4] + ay[5]) + (ay[6] + ay[7]));
    // self-loop contribution
    float mh  = (head == 0) ? m0 : m1;
    float esh = (head == 0) ? es0 : es1;
    float psh = __expf(esh - mh);
    {
        unsigned u = ((const unsigned*)(Hb + (size_t)d * 128))[lane];
        axs = fmaf(psh, __uint_as_float(u << 16), axs);
        ays = fmaf(psh, __uint_as_float(u & 0xffff0000u), ays);
    }
    #pragma unroll
    for (int off = 32; off; off >>= 1) {
        l0 += __shfl_xor(l0, off);
        if (H == 2) l1 += __shfl_xor(l1, off);
    }
    float denom = ((head == 0) ? l0 : l1) + psh;
    float inv = 1.f / (denom + 1e-16f);
    float o0 = axs * inv + bias[2 * lane];
    float o1 = ays * inv + bias[2 * lane + 1];
    if (DO_ELU) {
        o0 = o0 > 0.f ? o0 : expm1f(o0);
        o1 = o1 > 0.f ? o1 : expm1f(o1);
    }
    ((float2*)(out + (size_t)d * 128))[lane] = make_float2(o0, o1);
}

// ---------------- launch ----------------
extern "C" void kernel_launch(void* const* d_in, const int* in_sizes, int n_in,
                              void* d_out, int out_size, void* d_ws, size_t ws_size,
                              hipStream_t stream) {
    const float* x      = (const float*)d_in[0];
    const int*   ei     = (const int*)d_in[1];
    const float* W1     = (const float*)d_in[2];
    const float* a_src1 = (const float*)d_in[3];
    const float* a_dst1 = (const float*)d_in[4];
    const float* b1     = (const float*)d_in[5];
    const float* W2     = (const float*)d_in[6];
    const float* a_src2 = (const float*)d_in[7];
    const float* a_dst2 = (const float*)d_in[8];
    const float* b2     = (const float*)d_in[9];
    float* out = (float*)d_out;

    char* ws = (char*)d_ws;
    size_t off = 0;
    auto alloc = [&](size_t bytes) { void* p = ws + off; off += (bytes + 255) & ~(size_t)255; return p; };
    int*   ptr    = (int*)alloc((N_NODES + 1) * sizeof(int));
    int*   gbcnt  = (int*)alloc(NBUCK * sizeof(int));
    int*   bbase  = (int*)alloc((NBUCK + 1) * sizeof(int));
    int*   bcur   = (int*)alloc(NBUCK * sizeof(int));
    int2*  bpairs = (int2*)alloc((size_t)N_EDGES * sizeof(int2));
    int*   csr    = (int*)alloc(N_EDGES * sizeof(int));
    float* x2     = (float*)alloc((size_t)N_NODES * 128 * sizeof(float));
    unsigned short* hb = (unsigned short*)alloc((size_t)N_NODES * 128 * sizeof(unsigned short));
    float* als    = (float*)alloc(N_NODES * 2 * sizeof(float));
    float* ald    = (float*)alloc(N_NODES * 2 * sizeof(float));

    // ---- CSR build (bucket sort; same graph both layers) ----
    zerobuf_kernel<<<1, 256, 0, stream>>>(gbcnt);
    bucketcount_kernel<<<256, 256, 0, stream>>>(ei, gbcnt);
    bucketscan_kernel<<<1, 256, 0, stream>>>(gbcnt, bbase, bcur);
    bucketscatter_kernel<<<(N_EDGES + CCHUNK - 1) / CCHUNK, 256, 0, stream>>>(ei, bcur, bpairs);
    csrfinalize_kernel<<<NBUCK, 256, 0, stream>>>(bpairs, bbase, ptr, csr);

    int gblocks = (N_NODES + GB_ROWS - 1) / GB_ROWS;
    int wblocks = (N_NODES + 3) / 4;

    // ---- layer 1 ----
    gemm_kernel<2><<<gblocks, 256, 0, stream>>>(x, W1, a_src1, a_dst1, hb, als, ald, N_NODES);
    aggregate_kernel<2, 1><<<wblocks, 256, 0, stream>>>(hb, als, ald, ptr, csr, b1, x2);

    // ---- layer 2 ----
    gemm_kernel<1><<<gblocks, 256, 0, stream>>>(x2, W2, a_src2, a_dst2, hb, als, ald, N_NODES);
    aggregate_kernel<1, 0><<<wblocks, 256, 0, stream>>>(hb, als, ald, ptr, csr, b2, out);
}